// Round 1
// baseline (43.319 us; speedup 1.0000x reference)
//
#include <hip/hip_runtime.h>

// Problem constants (from reference setup_inputs)
#define BS    128
#define CH    8
#define NSC   3276
#define TSYM  14
#define NRE   12
#define HB_STRIDE (CH*NSC)            // h_hat batch stride = 26208
#define NK    (TSYM*NRE)              // 168
#define HOUT_FLOATS (BS*NSC*TSYM*CH)  // 46,964,736
#define N4H   (HOUT_FLOATS/4)         // 11,741,184 float4s for h_out
#define PE_FLOATS (NSC*TSYM*2)        // 91,728
#define N4    (N4H + PE_FLOATS/4)     // 11,764,116 total float4s

// ws layout:
//   int  view  [0 .. 168)              : nn table, flat k-order (k = a*12 + j)
//   float view [256 .. 256+336)        : pe_norm[j*28 + a*2 + e]
//   float view [1024 .. 1024+128*168)  : w[b*168 + a*12 + j]
#define WS_PE 256
#define WS_W  1024

__global__ void k_precompute(const int* __restrict__ sym_pos,
                             const int* __restrict__ sc_pos,
                             float* __restrict__ wsf,
                             int* __restrict__ wsi)
{
    __shared__ int   s_sc[6], s_sym[2];
    __shared__ float s_pe[NK * 2];
    __shared__ int   s_nn[NK];
    __shared__ float s_mean[2], s_rstd[2];

    int tid = threadIdx.x;
    if (tid < 6) s_sc[tid]  = sc_pos[tid];
    if (tid < 2) s_sym[tid] = sym_pos[tid];
    __syncthreads();

    if (tid < NK) {
        // grid flat order: k = r*14 + t  (r = RE in PRB, t = OFDM symbol)
        int r = tid / TSYM;
        int t = tid % TSYM;
        int best = 0x7fffffff, bestm = 0;
        int min0 = 0x7fffffff, min1 = 0x7fffffff;
        #pragma unroll
        for (int m = 0; m < 12; ++m) {
            int i = m >> 1, j = m & 1;          // pp[m] = (sc[i], sym[j])
            int d0 = abs(r - s_sc[i]);
            int d1 = abs(t - s_sym[j]);
            int d  = d0 + d1;
            if (d < best) { best = d; bestm = m; }  // first-tie-wins (argmin)
            if (d0 < min0) min0 = d0;
            if (d1 < min1) min1 = d1;
        }
        s_nn[tid]        = bestm;
        s_pe[tid*2 + 0]  = (float)min0;
        s_pe[tid*2 + 1]  = (float)min1;
    }
    __syncthreads();

    if (tid == 0) {
        #pragma unroll
        for (int e = 0; e < 2; ++e) {
            float sum = 0.f;
            for (int k = 0; k < NK; ++k) sum += s_pe[k*2 + e];
            float mean = sum / (float)NK;
            float ss = 0.f;
            for (int k = 0; k < NK; ++k) {
                float d = s_pe[k*2 + e] - mean;
                ss += d * d;
            }
            float sd = sqrtf(ss / (float)(NK - 1));   // ddof=1
            s_mean[e] = mean;
            s_rstd[e] = (sd > 0.f) ? (1.f / sd) : 1.f;
        }
    }
    __syncthreads();

    if (tid < NK) {
        // reshape-scramble: flat k reinterpreted as (a, j) = (k/12, k%12)
        int a = tid / NRE;
        int j = tid % NRE;
        float p0 = (s_pe[tid*2 + 0] - s_mean[0]) * s_rstd[0];
        float p1 = (s_pe[tid*2 + 1] - s_mean[1]) * s_rstd[1];
        // pe after transpose(1,0,2): pe_norm[j][a][e]
        wsf[WS_PE + (j*TSYM + a)*2 + 0] = p0;
        wsf[WS_PE + (j*TSYM + a)*2 + 1] = p1;
        wsi[tid] = s_nn[tid];
    }
}

__global__ void k_build_w(const float* __restrict__ h_hat,
                          const int* __restrict__ wsi,
                          float* __restrict__ wsf)
{
    int idx = blockIdx.x * blockDim.x + threadIdx.x;
    if (idx >= BS * NK) return;
    int b = idx / NK;
    int k = idx % NK;                 // k = a*12 + j
    int m = wsi[k];                   // m in [0,12)
    const float* hb = h_hat + (size_t)b * HB_STRIDE;  // channel 0, tx 0
    // v[b][m] = focc mean of pair at h_ls[...,6m]
    float v = 0.5f * (hb[6*m] + hb[6*m + 1]);
    wsf[WS_W + idx] = v;
}

__global__ void k_fill(const float* __restrict__ wsf, float4* __restrict__ out)
{
    unsigned stride = gridDim.x * blockDim.x;
    for (unsigned q = blockIdx.x * blockDim.x + threadIdx.x; q < N4; q += stride) {
        if (q < N4H) {
            // h_out[b][0][f][t][c] ; float4 q -> floats 4q..4q+3 (within one (b,f,t))
            unsigned r  = q >> 1;            // (b*3276 + f)*14 + t
            unsigned t  = r % TSYM;
            unsigned rf = r / TSYM;
            unsigned f  = rf % NSC;
            unsigned b  = rf / NSC;
            unsigned j  = f % NRE;
            float v = wsf[WS_W + b*NK + t*NRE + j];
            out[q] = make_float4(v, v, v, v);
        } else {
            // pe region: float index l within pe = 4*(q - N4H) .. +3
            unsigned l = (q - N4H) * 4;
            float vals[4];
            #pragma unroll
            for (int x = 0; x < 4; ++x) {
                unsigned li  = l + x;
                unsigned pp  = li / 28;        // subcarrier (tiled)
                unsigned rem = li % 28;        // a*2 + e
                unsigned jj  = pp % NRE;
                vals[x] = wsf[WS_PE + jj*28 + rem];
            }
            out[q] = make_float4(vals[0], vals[1], vals[2], vals[3]);
        }
    }
}

extern "C" void kernel_launch(void* const* d_in, const int* in_sizes, int n_in,
                              void* d_out, int out_size, void* d_ws, size_t ws_size,
                              hipStream_t stream) {
    const float* h_hat = (const float*)d_in[1];
    const int*   sym   = (const int*)d_in[2];
    const int*   sc    = (const int*)d_in[3];
    float* out = (float*)d_out;
    float* wsf = (float*)d_ws;
    int*   wsi = (int*)d_ws;

    hipLaunchKernelGGL(k_precompute, dim3(1),    dim3(256), 0, stream, sym, sc, wsf, wsi);
    hipLaunchKernelGGL(k_build_w,    dim3(84),   dim3(256), 0, stream, h_hat, wsi, wsf);
    hipLaunchKernelGGL(k_fill,       dim3(2048), dim3(256), 0, stream, wsf, out ? (float4*)out : nullptr);
}

// Round 2
// 34.858 us; speedup vs baseline: 1.2427x; 1.2427x over previous
//
#include <hip/hip_runtime.h>

// Problem constants (from reference setup_inputs)
#define BS    128
#define CH    8
#define NSC   3276
#define TSYM  14
#define NRE   12
#define HB_STRIDE (CH*NSC)            // h_hat batch stride = 26208
#define NK    168                     // 14*12
#define Q4_PER_B 91728                // float4s per batch in h_out (3276*14*8/4)
#define SLABS 16
#define Q4_SLAB (Q4_PER_B/SLABS)      // 5733
#define N4H   (BS*Q4_PER_B)           // 11,741,184 float4s (h_out)
#define PE4   22932                   // pe float4 count (3276*14*2/4)
#define PE_BLOCKS 12
#define HOUT_BLOCKS (BS*SLABS)        // 2048

__global__ __launch_bounds__(256)
void k_fused(const float* __restrict__ h_hat,
             const int* __restrict__ sym_pos,
             const int* __restrict__ sc_pos,
             float4* __restrict__ out)
{
    const int tid = threadIdx.x;
    const int bid = blockIdx.x;

    __shared__ int s_sc[6], s_sym[2];
    __shared__ int s_nn[NK];

    if (tid < 6) s_sc[tid]  = sc_pos[tid];
    if (tid < 2) s_sym[tid] = sym_pos[tid];
    __syncthreads();

    // nn table in flat argmin order (k = r*14 + t), pe distances in registers
    float d0f = 0.f, d1f = 0.f;
    if (tid < NK) {
        int r = tid / TSYM, t = tid % TSYM;
        int best = 1 << 30, bestm = 0, min0 = 1 << 30, min1 = 1 << 30;
        #pragma unroll
        for (int m = 0; m < 12; ++m) {
            int i = m >> 1, j = m & 1;            // pp[m] = (sc[i], sym[j])
            int d0 = abs(r - s_sc[i]);
            int d1 = abs(t - s_sym[j]);
            int d  = d0 + d1;
            if (d < best) { best = d; bestm = m; }  // first-tie-wins
            if (d0 < min0) min0 = d0;
            if (d1 < min1) min1 = d1;
        }
        s_nn[tid] = bestm;
        d0f = (float)min0;
        d1f = (float)min1;
    }

    if (bid < HOUT_BLOCKS) {
        // ---- h_out fill: one block per (batch, slab) ----
        const int b = bid >> 4, slab = bid & 15;
        __shared__ float s_v[12];
        __shared__ float s_w2[NK];   // s_w2[(f%12)*14 + t]
        if (tid < 12) {
            const float* hb = h_hat + (size_t)b * HB_STRIDE;  // ch 0, tx 0
            s_v[tid] = 0.5f * (hb[6 * tid] + hb[6 * tid + 1]); // focc mean
        }
        __syncthreads();
        if (tid < NK) {
            int jj = tid / TSYM, tt = tid % TSYM;
            // reference reads nn at reshaped (t, j) = flat t*12 + j
            s_w2[tid] = s_v[s_nn[tt * NRE + jj]];
        }
        __syncthreads();

        float4* ob = out + (size_t)b * Q4_PER_B;
        const int base = slab * Q4_SLAB;
        for (int i = tid; i < Q4_SLAB; i += 256) {
            unsigned qb = base + i;
            unsigned r  = qb >> 1;        // r = f*14 + t (8 floats per r)
            unsigned rm = r % 168u;       // = (f%12)*14 + t
            float v = s_w2[rm];
            ob[qb] = make_float4(v, v, v, v);
        }
    } else {
        // ---- pe fill: 12 blocks ----
        __shared__ float s_pe[2][NK];
        __shared__ float s_ms[4];        // mean0, mean1, rstd0, rstd1
        if (tid < NK) { s_pe[0][tid] = d0f; s_pe[1][tid] = d1f; }
        __syncthreads();

        const int wv = tid >> 6, ln = tid & 63;
        if (wv < 2) {
            float sum = 0.f;
            for (int k = ln; k < NK; k += 64) sum += s_pe[wv][k];
            for (int o = 32; o > 0; o >>= 1) sum += __shfl_down(sum, o, 64);
            if (ln == 0) s_ms[wv] = sum / (float)NK;
        }
        __syncthreads();
        if (wv < 2) {
            float mean = s_ms[wv];
            float ss = 0.f;
            for (int k = ln; k < NK; k += 64) {
                float d = s_pe[wv][k] - mean;
                ss += d * d;
            }
            for (int o = 32; o > 0; o >>= 1) ss += __shfl_down(ss, o, 64);
            if (ln == 0) {
                float sd = sqrtf(ss / (float)(NK - 1));   // ddof=1
                s_ms[2 + wv] = (sd > 0.f) ? (1.f / sd) : 1.f;
            }
        }
        __syncthreads();

        __shared__ float s_pen[336];     // pe pattern [j*28 + a*2 + e]
        if (tid < NK) {
            int a = tid / NRE, j = tid % NRE;   // flat k -> (a, j) reshape
            s_pen[(j * TSYM + a) * 2 + 0] = (s_pe[0][tid] - s_ms[0]) * s_ms[2];
            s_pen[(j * TSYM + a) * 2 + 1] = (s_pe[1][tid] - s_ms[1]) * s_ms[3];
        }
        __syncthreads();

        const float4* pen4 = (const float4*)s_pen;   // 84 float4s
        const int pb = bid - HOUT_BLOCKS;            // 0..11
        for (int qp = pb * 256 + tid; qp < PE4; qp += PE_BLOCKS * 256) {
            out[N4H + qp] = pen4[qp % 84u];
        }
    }
}

extern "C" void kernel_launch(void* const* d_in, const int* in_sizes, int n_in,
                              void* d_out, int out_size, void* d_ws, size_t ws_size,
                              hipStream_t stream) {
    const float* h_hat = (const float*)d_in[1];
    const int*   sym   = (const int*)d_in[2];
    const int*   sc    = (const int*)d_in[3];
    hipLaunchKernelGGL(k_fused, dim3(HOUT_BLOCKS + PE_BLOCKS), dim3(256), 0, stream,
                       h_hat, sym, sc, (float4*)d_out);
}